// Round 1
// baseline (1068.322 us; speedup 1.0000x reference)
//
#include <hip/hip_runtime.h>
#include <hip/hip_bf16.h>

#define LRELU(v) ((v) >= 0.f ? (v) : 0.2f * (v))

// ---------------- feature-norm stats for x ----------------
__global__ __launch_bounds__(256) void xstats_kernel(const float4* __restrict__ x4,
                                                     float* __restrict__ xstats, int n4) {
    __shared__ float ls[32];
    if (threadIdx.x < 32) ls[threadIdx.x] = 0.f;
    __syncthreads();
    float s1[4] = {0,0,0,0}, s2[4] = {0,0,0,0};
    int stride = gridDim.x * blockDim.x;
    int j4 = (threadIdx.x & 3) * 4;  // stride % 4 == 0 -> constant per thread
    for (int i = blockIdx.x * blockDim.x + threadIdx.x; i < n4; i += stride) {
        float4 v = x4[i];
        s1[0] += v.x; s2[0] += v.x * v.x;
        s1[1] += v.y; s2[1] += v.y * v.y;
        s1[2] += v.z; s2[2] += v.z * v.z;
        s1[3] += v.w; s2[3] += v.w * v.w;
    }
    #pragma unroll
    for (int k = 0; k < 4; ++k) {
        atomicAdd(&ls[j4 + k], s1[k]);
        atomicAdd(&ls[16 + j4 + k], s2[k]);
    }
    __syncthreads();
    if (threadIdx.x < 32) atomicAdd(&xstats[threadIdx.x], ls[threadIdx.x]);
}

__global__ __launch_bounds__(256) void xnorm_kernel(const float4* __restrict__ x4,
                                                    float4* __restrict__ xn4,
                                                    const float* __restrict__ xstats,
                                                    int n4, float invN) {
    int stride = gridDim.x * blockDim.x;
    for (int i = blockIdx.x * blockDim.x + threadIdx.x; i < n4; i += stride) {
        int j4 = (i & 3) * 4;
        float4 v = x4[i];
        float o[4], in[4] = {v.x, v.y, v.z, v.w};
        #pragma unroll
        for (int k = 0; k < 4; ++k) {
            float mu = xstats[j4 + k] * invN;
            float var = xstats[16 + j4 + k] * invN - mu * mu;
            o[k] = (in[k] - mu) * rsqrtf(var + 1e-5f);
        }
        xn4[i] = make_float4(o[0], o[1], o[2], o[3]);
    }
}

// ---------------- edge pass: degree histogram + raw edge-attr scatter + stats ----------------
__global__ __launch_bounds__(256) void edge_pass1(const float4* __restrict__ eattr,
                                                  const int* __restrict__ ei,
                                                  int* __restrict__ deg,
                                                  float* __restrict__ EA,
                                                  float* __restrict__ estats, int E) {
    __shared__ float ls[8];
    if (threadIdx.x < 8) ls[threadIdx.x] = 0.f;
    __syncthreads();
    float s1[4] = {0,0,0,0}, s2[4] = {0,0,0,0};
    int stride = gridDim.x * blockDim.x;
    for (int e = blockIdx.x * blockDim.x + threadIdx.x; e < E; e += stride) {
        float4 v = eattr[e];
        int dst = ei[E + e];
        atomicAdd(&deg[dst], 1);
        float* p = EA + (size_t)dst * 4;
        atomicAdd(p + 0, v.x); atomicAdd(p + 1, v.y);
        atomicAdd(p + 2, v.z); atomicAdd(p + 3, v.w);
        s1[0] += v.x; s2[0] += v.x * v.x;
        s1[1] += v.y; s2[1] += v.y * v.y;
        s1[2] += v.z; s2[2] += v.z * v.z;
        s1[3] += v.w; s2[3] += v.w * v.w;
    }
    #pragma unroll
    for (int k = 0; k < 4; ++k) {
        atomicAdd(&ls[k], s1[k]);
        atomicAdd(&ls[4 + k], s2[k]);
    }
    __syncthreads();
    if (threadIdx.x < 8) atomicAdd(&estats[threadIdx.x], ls[threadIdx.x]);
}

// ---------------- exclusive prefix scan of degrees (single block) ----------------
__global__ __launch_bounds__(1024) void scan_kernel(const int* __restrict__ deg,
                                                    int* __restrict__ offsets, int N) {
    __shared__ int wsum[16];
    __shared__ int chunk_total;
    int lane = threadIdx.x & 63, w = threadIdx.x >> 6;
    int run = 0;
    for (int base = 0; base < N; base += 1024) {
        int i = base + threadIdx.x;
        int v = (i < N) ? deg[i] : 0;
        int inc = v;
        #pragma unroll
        for (int d = 1; d < 64; d <<= 1) {
            int t = __shfl_up(inc, d);
            if (lane >= d) inc += t;
        }
        if (lane == 63) wsum[w] = inc;
        __syncthreads();
        if (threadIdx.x == 0) {
            int s = 0;
            for (int k = 0; k < 16; ++k) { int t = wsum[k]; wsum[k] = s; s += t; }
            chunk_total = s;
        }
        __syncthreads();
        if (i < N) offsets[i] = run + wsum[w] + inc - v;  // exclusive
        run += chunk_total;
        __syncthreads();
    }
    if (threadIdx.x == 0) offsets[N] = run;
}

// ---------------- scatter src ids into dst-sorted CSR ----------------
__global__ __launch_bounds__(256) void edge_scatter(const int* __restrict__ ei,
                                                    const int* __restrict__ offsets,
                                                    int* __restrict__ cursor,
                                                    int* __restrict__ src_sorted, int E) {
    int stride = gridDim.x * blockDim.x;
    for (int e = blockIdx.x * blockDim.x + threadIdx.x; e < E; e += stride) {
        int dst = ei[E + e];
        int pos = offsets[dst] + atomicAdd(&cursor[dst], 1);
        src_sorted[pos] = ei[e];
    }
}

// ---------------- finalize EA: fold featnorm of edge_attr analytically ----------------
__global__ __launch_bounds__(256) void finalize_ea(float* __restrict__ EA,
                                                   const int* __restrict__ offsets,
                                                   const float* __restrict__ estats,
                                                   int N, float invE) {
    int stride = gridDim.x * blockDim.x;
    float mu[4], rs[4];
    #pragma unroll
    for (int j = 0; j < 4; ++j) {
        mu[j] = estats[j] * invE;
        float var = estats[4 + j] * invE - mu[j] * mu[j];
        rs[j] = rsqrtf(var + 1e-5f);
    }
    for (int n = blockIdx.x * blockDim.x + threadIdx.x; n < N; n += stride) {
        float indeg = (float)(offsets[n + 1] - offsets[n]);
        float4 v = *(float4*)(EA + (size_t)n * 4);
        v.x = (v.x - indeg * mu[0]) * rs[0];
        v.y = (v.y - indeg * mu[1]) * rs[1];
        v.z = (v.z - indeg * mu[2]) * rs[2];
        v.w = (v.w - indeg * mu[3]) * rs[3];
        *(float4*)(EA + (size_t)n * 4) = v;
    }
}

// ---------------- fused conv layer: CSR SpMM gather + node update ----------------
// one wave per node; 4 groups of 16 lanes each handle one edge, lane%16 = feature slot
template <int FIN>
__global__ __launch_bounds__(256) void conv_kernel(const float* __restrict__ hin,
                                                   const float* __restrict__ EA,
                                                   const int* __restrict__ offsets,
                                                   const int* __restrict__ src_sorted,
                                                   const float* __restrict__ Wr,
                                                   const float* __restrict__ Wm,
                                                   const float* __restrict__ b,
                                                   float* __restrict__ hout, int N) {
    __shared__ float gbuf[4][48];
    __shared__ float hbuf[4][FIN];
    int w = threadIdx.x >> 6;
    int lane = threadIdx.x & 63;
    int node = blockIdx.x * 4 + w;
    if (node < N) {
        int s0 = offsets[node], s1 = offsets[node + 1];
        int g = lane >> 4, fl = lane & 15;
        float a0 = 0.f, a1 = 0.f, a2 = 0.f;
        for (int e = s0 + g; e < s1; e += 4) {
            int s = src_sorted[e];
            const float* hp = hin + (size_t)s * FIN;
            a0 += hp[fl];
            if (FIN > 16) { a1 += hp[16 + fl]; a2 += hp[32 + fl]; }
        }
        a0 += __shfl_xor(a0, 16); a0 += __shfl_xor(a0, 32);
        if (FIN > 16) {
            a1 += __shfl_xor(a1, 16); a1 += __shfl_xor(a1, 32);
            a2 += __shfl_xor(a2, 16); a2 += __shfl_xor(a2, 32);
        }
        if (lane < 16) {
            gbuf[w][lane] = a0;
            if (FIN > 16) { gbuf[w][16 + lane] = a1; gbuf[w][32 + lane] = a2; }
        }
        if (lane < FIN) hbuf[w][lane] = hin[(size_t)node * FIN + lane];
    }
    __syncthreads();
    if (node < N && lane < 48) {
        int f = lane;
        float acc = b[f];
        #pragma unroll
        for (int k = 0; k < FIN; ++k)
            acc += hbuf[w][k] * Wr[k * 48 + f] + gbuf[w][k] * Wm[k * 48 + f];
        float4 ea = *(const float4*)(EA + (size_t)node * 4);
        acc += ea.x * Wm[(FIN + 0) * 48 + f] + ea.y * Wm[(FIN + 1) * 48 + f]
             + ea.z * Wm[(FIN + 2) * 48 + f] + ea.w * Wm[(FIN + 3) * 48 + f];
        hout[(size_t)node * 48 + f] = LRELU(acc);
    }
}

// ---------------- per-graph mean readout (batch is sorted) ----------------
__global__ __launch_bounds__(256) void readout_kernel(const float* __restrict__ h,
                                                      const int* __restrict__ batch,
                                                      float* __restrict__ hcat, int N, int l) {
    int g = blockIdx.x;
    // lower_bound(batch, g) and lower_bound(batch, g+1)
    int lo = 0, hi = N;
    while (lo < hi) { int m = (lo + hi) >> 1; if (batch[m] < g) lo = m + 1; else hi = m; }
    int start = lo;
    hi = N;
    while (lo < hi) { int m = (lo + hi) >> 1; if (batch[m] < g + 1) lo = m + 1; else hi = m; }
    int end = lo;
    __shared__ float sred[4][48];
    int w = threadIdx.x >> 6, lane = threadIdx.x & 63;
    float acc = 0.f;
    if (lane < 48)
        for (int n = start + w; n < end; n += 4) acc += h[(size_t)n * 48 + lane];
    if (lane < 48) sred[w][lane] = acc;
    __syncthreads();
    int t = threadIdx.x;
    if (t < 48) {
        float s = sred[0][t] + sred[1][t] + sred[2][t] + sred[3][t];
        float cnt = (float)(end - start);
        hcat[g * 144 + l * 48 + t] = s / fmaxf(cnt, 1.f);
    }
}

// ---------------- final MLP: one block per graph ----------------
__global__ __launch_bounds__(128) void mlp_kernel(const float* __restrict__ hcat,
                                                  const float* __restrict__ Wl1, const float* __restrict__ bl1,
                                                  const float* __restrict__ Wl2, const float* __restrict__ bl2,
                                                  const float* __restrict__ Wf, const float* __restrict__ bf,
                                                  float* __restrict__ out) {
    int g = blockIdx.x, t = threadIdx.x;
    __shared__ float buf[144];
    __shared__ float l1[128];
    for (int i = t; i < 144; i += 128) buf[i] = hcat[g * 144 + i];
    __syncthreads();
    float acc = bl1[t];
    for (int k = 0; k < 144; ++k) acc += buf[k] * Wl1[k * 128 + t];
    acc = LRELU(acc);
    l1[t] = acc;
    __syncthreads();
    float acc2 = bl2[t];
    for (int k = 0; k < 128; ++k) acc2 += l1[k] * Wl2[k * 128 + t];
    acc2 = LRELU(acc2);
    __syncthreads();          // all l1 reads done before buf reuse below
    buf[t] = acc2;
    __syncthreads();
    if (t < 4) {
        float a = bf[t];
        for (int k = 0; k < 128; ++k) a += buf[k] * Wf[k * 4 + t];
        out[g * 4 + t] = a;
    }
}

extern "C" void kernel_launch(void* const* d_in, const int* in_sizes, int n_in,
                              void* d_out, int out_size, void* d_ws, size_t ws_size,
                              hipStream_t stream) {
    const float* x     = (const float*)d_in[0];
    const float* eattr = (const float*)d_in[1];
    const float* Wr0 = (const float*)d_in[2];
    const float* Wm0 = (const float*)d_in[3];
    const float* b0  = (const float*)d_in[4];
    const float* Wr1 = (const float*)d_in[5];
    const float* Wm1 = (const float*)d_in[6];
    const float* b1  = (const float*)d_in[7];
    const float* Wr2 = (const float*)d_in[8];
    const float* Wm2 = (const float*)d_in[9];
    const float* b2  = (const float*)d_in[10];
    const float* Wl1 = (const float*)d_in[11];
    const float* bl1 = (const float*)d_in[12];
    const float* Wl2 = (const float*)d_in[13];
    const float* bl2 = (const float*)d_in[14];
    const float* Wf  = (const float*)d_in[15];
    const float* bf  = (const float*)d_in[16];
    const int* ei    = (const int*)d_in[17];
    const int* batch = (const int*)d_in[18];

    int N = in_sizes[0] / 16;
    int E = in_sizes[1] / 4;

    float* ws = (float*)d_ws;
    float* xn     = ws;                           // N*16
    float* h0     = xn + (size_t)N * 16;          // N*48
    float* h1     = h0 + (size_t)N * 48;          // N*48
    float* EA     = h1 + (size_t)N * 48;          // N*4
    float* estats = EA + (size_t)N * 4;           // 8
    float* xstats = estats + 8;                   // 32
    float* hcat   = xstats + 32;                  // 64*144
    int* deg        = (int*)(hcat + 64 * 144);    // N
    int* offsets    = deg + N;                    // N+1
    int* cursor     = offsets + N + 1;            // N
    int* src_sorted = cursor + N;                 // E

    // zero accumulators (EA, estats, xstats contiguous; deg..cursor contiguous)
    hipMemsetAsync(EA, 0, ((size_t)N * 4 + 40) * sizeof(float), stream);
    hipMemsetAsync(deg, 0, (size_t)(3 * N + 1) * sizeof(int), stream);

    int n4 = N * 4;  // float4 count of x
    xstats_kernel<<<256, 256, 0, stream>>>((const float4*)x, xstats, n4);
    xnorm_kernel<<<256, 256, 0, stream>>>((const float4*)x, (float4*)xn, xstats, n4, 1.f / N);
    edge_pass1<<<1024, 256, 0, stream>>>((const float4*)eattr, ei, deg, EA, estats, E);
    scan_kernel<<<1, 1024, 0, stream>>>(deg, offsets, N);
    edge_scatter<<<2048, 256, 0, stream>>>(ei, offsets, cursor, src_sorted, E);
    finalize_ea<<<(N + 255) / 256, 256, 0, stream>>>(EA, offsets, estats, N, 1.f / E);

    conv_kernel<16><<<(N + 3) / 4, 256, 0, stream>>>(xn, EA, offsets, src_sorted, Wr0, Wm0, b0, h0, N);
    readout_kernel<<<64, 256, 0, stream>>>(h0, batch, hcat, N, 0);
    conv_kernel<48><<<(N + 3) / 4, 256, 0, stream>>>(h0, EA, offsets, src_sorted, Wr1, Wm1, b1, h1, N);
    readout_kernel<<<64, 256, 0, stream>>>(h1, batch, hcat, N, 1);
    conv_kernel<48><<<(N + 3) / 4, 256, 0, stream>>>(h1, EA, offsets, src_sorted, Wr2, Wm2, b2, h0, N);
    readout_kernel<<<64, 256, 0, stream>>>(h0, batch, hcat, N, 2);

    mlp_kernel<<<64, 128, 0, stream>>>(hcat, Wl1, bl1, Wl2, bl2, Wf, bf, (float*)d_out);
}

// Round 3
// 679.962 us; speedup vs baseline: 1.5711x; 1.5711x over previous
//
#include <hip/hip_runtime.h>
#include <hip/hip_bf16.h>

#define LRELU(v) ((v) >= 0.f ? (v) : 0.2f * (v))

// ---------------- feature-norm stats for x ----------------
__global__ __launch_bounds__(256) void xstats_kernel(const float4* __restrict__ x4,
                                                     float* __restrict__ xstats, int n4) {
    __shared__ float ls[32];
    if (threadIdx.x < 32) ls[threadIdx.x] = 0.f;
    __syncthreads();
    float s1[4] = {0,0,0,0}, s2[4] = {0,0,0,0};
    int stride = gridDim.x * blockDim.x;
    int j4 = (threadIdx.x & 3) * 4;  // stride % 4 == 0 -> constant per thread
    for (int i = blockIdx.x * blockDim.x + threadIdx.x; i < n4; i += stride) {
        float4 v = x4[i];
        s1[0] += v.x; s2[0] += v.x * v.x;
        s1[1] += v.y; s2[1] += v.y * v.y;
        s1[2] += v.z; s2[2] += v.z * v.z;
        s1[3] += v.w; s2[3] += v.w * v.w;
    }
    #pragma unroll
    for (int k = 0; k < 4; ++k) {
        atomicAdd(&ls[j4 + k], s1[k]);
        atomicAdd(&ls[16 + j4 + k], s2[k]);
    }
    __syncthreads();
    if (threadIdx.x < 32) atomicAdd(&xstats[threadIdx.x], ls[threadIdx.x]);
}

__global__ __launch_bounds__(256) void xnorm_kernel(const float4* __restrict__ x4,
                                                    float4* __restrict__ xn4,
                                                    const float* __restrict__ xstats,
                                                    int n4, float invN) {
    int stride = gridDim.x * blockDim.x;
    for (int i = blockIdx.x * blockDim.x + threadIdx.x; i < n4; i += stride) {
        int j4 = (i & 3) * 4;
        float4 v = x4[i];
        float o[4], in[4] = {v.x, v.y, v.z, v.w};
        #pragma unroll
        for (int k = 0; k < 4; ++k) {
            float mu = xstats[j4 + k] * invN;
            float var = xstats[16 + j4 + k] * invN - mu * mu;
            o[k] = (in[k] - mu) * rsqrtf(var + 1e-5f);
        }
        xn4[i] = make_float4(o[0], o[1], o[2], o[3]);
    }
}

// ---------------- edge pass 1: degree histogram with rank capture + edge-attr stats ----------------
__global__ __launch_bounds__(256) void edge_rank(const float4* __restrict__ eattr,
                                                 const int* __restrict__ ei,
                                                 int* __restrict__ deg,
                                                 int* __restrict__ rank,
                                                 float* __restrict__ estats, int E) {
    __shared__ float ls[8];
    if (threadIdx.x < 8) ls[threadIdx.x] = 0.f;
    __syncthreads();
    float s1[4] = {0,0,0,0}, s2[4] = {0,0,0,0};
    int stride = gridDim.x * blockDim.x;
    for (int e = blockIdx.x * blockDim.x + threadIdx.x; e < E; e += stride) {
        int dst = ei[E + e];
        rank[e] = atomicAdd(&deg[dst], 1);
        float4 v = eattr[e];
        s1[0] += v.x; s2[0] += v.x * v.x;
        s1[1] += v.y; s2[1] += v.y * v.y;
        s1[2] += v.z; s2[2] += v.z * v.z;
        s1[3] += v.w; s2[3] += v.w * v.w;
    }
    #pragma unroll
    for (int k = 0; k < 4; ++k) {
        atomicAdd(&ls[k], s1[k]);
        atomicAdd(&ls[4 + k], s2[k]);
    }
    __syncthreads();
    if (threadIdx.x < 8) atomicAdd(&estats[threadIdx.x], ls[threadIdx.x]);
}

// ---------------- 3-phase exclusive scan of degrees ----------------
__global__ __launch_bounds__(256) void scanA(const int* __restrict__ deg,
                                             int* __restrict__ offs,
                                             int* __restrict__ bsum, int N) {
    int i = blockIdx.x * 256 + threadIdx.x;
    int v = (i < N) ? deg[i] : 0;
    int lane = threadIdx.x & 63, w = threadIdx.x >> 6;
    int inc = v;
    #pragma unroll
    for (int d = 1; d < 64; d <<= 1) {
        int u = __shfl_up(inc, d);
        if (lane >= d) inc += u;
    }
    __shared__ int wsum[4], woff[4];
    if (lane == 63) wsum[w] = inc;
    __syncthreads();
    if (threadIdx.x == 0) {
        int s = 0;
        #pragma unroll
        for (int k = 0; k < 4; ++k) { woff[k] = s; s += wsum[k]; }
        bsum[blockIdx.x] = s;
    }
    __syncthreads();
    if (i < N) offs[i] = woff[w] + inc - v;  // exclusive within block
}

__global__ __launch_bounds__(256) void scanB(const int* __restrict__ bsum,
                                             int* __restrict__ boff, int nb) {
    int t = threadIdx.x;
    int v = (t < nb) ? bsum[t] : 0;
    int lane = t & 63, w = t >> 6;
    int inc = v;
    #pragma unroll
    for (int d = 1; d < 64; d <<= 1) {
        int u = __shfl_up(inc, d);
        if (lane >= d) inc += u;
    }
    __shared__ int wsum[4], woff[4];
    if (lane == 63) wsum[w] = inc;
    __syncthreads();
    if (t == 0) {
        int s = 0;
        #pragma unroll
        for (int k = 0; k < 4; ++k) { woff[k] = s; s += wsum[k]; }
    }
    __syncthreads();
    if (t < nb) boff[t] = woff[w] + inc - v;
}

__global__ __launch_bounds__(256) void scanC(int* __restrict__ offs,
                                             const int* __restrict__ boff, int N, int E) {
    int i = blockIdx.x * 256 + threadIdx.x;
    if (i < N) offs[i] += boff[blockIdx.x];
    if (i == 0) offs[N] = E;
}

// ---------------- scatter src & edge ids into dst-sorted CSR (atomic-free) ----------------
__global__ __launch_bounds__(256) void edge_scatter(const int* __restrict__ ei,
                                                    const int* __restrict__ offsets,
                                                    const int* __restrict__ rank,
                                                    int* __restrict__ src_sorted,
                                                    int* __restrict__ eid_sorted, int E) {
    int stride = gridDim.x * blockDim.x;
    for (int e = blockIdx.x * blockDim.x + threadIdx.x; e < E; e += stride) {
        int dst = ei[E + e];
        int pos = offsets[dst] + rank[e];
        src_sorted[pos] = ei[e];
        eid_sorted[pos] = e;
    }
}

// ---------------- per-node edge-attr aggregation with analytic featnorm fold ----------------
// 16-lane group per node (4 nodes/wave, 16 nodes/block)
__global__ __launch_bounds__(256) void ea_sum(const float4* __restrict__ eattr,
                                              const int* __restrict__ offsets,
                                              const int* __restrict__ eid_sorted,
                                              const float* __restrict__ estats,
                                              float4* __restrict__ EA, int N, float invE) {
    int g = threadIdx.x >> 4, gl = threadIdx.x & 15;
    int node = blockIdx.x * 16 + g;
    if (node >= N) return;
    int s0 = offsets[node], s1 = offsets[node + 1];
    float4 acc = make_float4(0.f, 0.f, 0.f, 0.f);
    for (int e = s0 + gl; e < s1; e += 16) {
        float4 v = eattr[eid_sorted[e]];
        acc.x += v.x; acc.y += v.y; acc.z += v.z; acc.w += v.w;
    }
    #pragma unroll
    for (int d = 1; d < 16; d <<= 1) {
        acc.x += __shfl_xor(acc.x, d);
        acc.y += __shfl_xor(acc.y, d);
        acc.z += __shfl_xor(acc.z, d);
        acc.w += __shfl_xor(acc.w, d);
    }
    if (gl == 0) {
        float degf = (float)(s1 - s0);
        float mu0 = estats[0] * invE, rs0 = rsqrtf(estats[4] * invE - mu0 * mu0 + 1e-5f);
        float mu1 = estats[1] * invE, rs1 = rsqrtf(estats[5] * invE - mu1 * mu1 + 1e-5f);
        float mu2 = estats[2] * invE, rs2 = rsqrtf(estats[6] * invE - mu2 * mu2 + 1e-5f);
        float mu3 = estats[3] * invE, rs3 = rsqrtf(estats[7] * invE - mu3 * mu3 + 1e-5f);
        float4 o;
        o.x = (acc.x - degf * mu0) * rs0;
        o.y = (acc.y - degf * mu1) * rs1;
        o.z = (acc.z - degf * mu2) * rs2;
        o.w = (acc.w - degf * mu3) * rs3;
        EA[node] = o;
    }
}

// ---------------- fused conv layer: CSR SpMM gather + node update ----------------
// one wave per node; 4 groups of 16 lanes each handle one edge, lane%16 = feature slot
template <int FIN>
__global__ __launch_bounds__(256) void conv_kernel(const float* __restrict__ hin,
                                                   const float* __restrict__ EA,
                                                   const int* __restrict__ offsets,
                                                   const int* __restrict__ src_sorted,
                                                   const float* __restrict__ Wr,
                                                   const float* __restrict__ Wm,
                                                   const float* __restrict__ b,
                                                   float* __restrict__ hout, int N) {
    __shared__ float gbuf[4][48];
    __shared__ float hbuf[4][FIN];
    int w = threadIdx.x >> 6;
    int lane = threadIdx.x & 63;
    int node = blockIdx.x * 4 + w;
    if (node < N) {
        int s0 = offsets[node], s1 = offsets[node + 1];
        int g = lane >> 4, fl = lane & 15;
        float a0 = 0.f, a1 = 0.f, a2 = 0.f;
        for (int e = s0 + g; e < s1; e += 4) {
            int s = src_sorted[e];
            const float* hp = hin + (size_t)s * FIN;
            a0 += hp[fl];
            if (FIN > 16) { a1 += hp[16 + fl]; a2 += hp[32 + fl]; }
        }
        a0 += __shfl_xor(a0, 16); a0 += __shfl_xor(a0, 32);
        if (FIN > 16) {
            a1 += __shfl_xor(a1, 16); a1 += __shfl_xor(a1, 32);
            a2 += __shfl_xor(a2, 16); a2 += __shfl_xor(a2, 32);
        }
        if (lane < 16) {
            gbuf[w][lane] = a0;
            if (FIN > 16) { gbuf[w][16 + lane] = a1; gbuf[w][32 + lane] = a2; }
        }
        if (lane < FIN) hbuf[w][lane] = hin[(size_t)node * FIN + lane];
    }
    __syncthreads();
    if (node < N && lane < 48) {
        int f = lane;
        float acc = b[f];
        #pragma unroll
        for (int k = 0; k < FIN; ++k)
            acc += hbuf[w][k] * Wr[k * 48 + f] + gbuf[w][k] * Wm[k * 48 + f];
        float4 ea = *(const float4*)(EA + (size_t)node * 4);
        acc += ea.x * Wm[(FIN + 0) * 48 + f] + ea.y * Wm[(FIN + 1) * 48 + f]
             + ea.z * Wm[(FIN + 2) * 48 + f] + ea.w * Wm[(FIN + 3) * 48 + f];
        hout[(size_t)node * 48 + f] = LRELU(acc);
    }
}

// ---------------- per-graph mean readout (batch is sorted) ----------------
__global__ __launch_bounds__(256) void readout_kernel(const float* __restrict__ h,
                                                      const int* __restrict__ batch,
                                                      float* __restrict__ hcat, int N, int l) {
    int g = blockIdx.x;
    int lo = 0, hi = N;
    while (lo < hi) { int m = (lo + hi) >> 1; if (batch[m] < g) lo = m + 1; else hi = m; }
    int start = lo;
    hi = N;
    while (lo < hi) { int m = (lo + hi) >> 1; if (batch[m] < g + 1) lo = m + 1; else hi = m; }
    int end = lo;
    __shared__ float sred[4][48];
    int w = threadIdx.x >> 6, lane = threadIdx.x & 63;
    float acc = 0.f;
    if (lane < 48)
        for (int n = start + w; n < end; n += 4) acc += h[(size_t)n * 48 + lane];
    if (lane < 48) sred[w][lane] = acc;
    __syncthreads();
    int t = threadIdx.x;
    if (t < 48) {
        float s = sred[0][t] + sred[1][t] + sred[2][t] + sred[3][t];
        float cnt = (float)(end - start);
        hcat[g * 144 + l * 48 + t] = s / fmaxf(cnt, 1.f);
    }
}

// ---------------- final MLP: one block per graph ----------------
__global__ __launch_bounds__(128) void mlp_kernel(const float* __restrict__ hcat,
                                                  const float* __restrict__ Wl1, const float* __restrict__ bl1,
                                                  const float* __restrict__ Wl2, const float* __restrict__ bl2,
                                                  const float* __restrict__ Wf, const float* __restrict__ bf,
                                                  float* __restrict__ out) {
    int g = blockIdx.x, t = threadIdx.x;
    __shared__ float buf[144];
    __shared__ float l1[128];
    for (int i = t; i < 144; i += 128) buf[i] = hcat[g * 144 + i];
    __syncthreads();
    float acc = bl1[t];
    for (int k = 0; k < 144; ++k) acc += buf[k] * Wl1[k * 128 + t];
    acc = LRELU(acc);
    l1[t] = acc;
    __syncthreads();
    float acc2 = bl2[t];
    for (int k = 0; k < 128; ++k) acc2 += l1[k] * Wl2[k * 128 + t];
    acc2 = LRELU(acc2);
    __syncthreads();
    buf[t] = acc2;
    __syncthreads();
    if (t < 4) {
        float a = bf[t];
        for (int k = 0; k < 128; ++k) a += buf[k] * Wf[k * 4 + t];
        out[g * 4 + t] = a;
    }
}

extern "C" void kernel_launch(void* const* d_in, const int* in_sizes, int n_in,
                              void* d_out, int out_size, void* d_ws, size_t ws_size,
                              hipStream_t stream) {
    const float* x     = (const float*)d_in[0];
    const float* eattr = (const float*)d_in[1];
    const float* Wr0 = (const float*)d_in[2];
    const float* Wm0 = (const float*)d_in[3];
    const float* b0  = (const float*)d_in[4];
    const float* Wr1 = (const float*)d_in[5];
    const float* Wm1 = (const float*)d_in[6];
    const float* b1  = (const float*)d_in[7];
    const float* Wr2 = (const float*)d_in[8];
    const float* Wm2 = (const float*)d_in[9];
    const float* b2  = (const float*)d_in[10];
    const float* Wl1 = (const float*)d_in[11];
    const float* bl1 = (const float*)d_in[12];
    const float* Wl2 = (const float*)d_in[13];
    const float* bl2 = (const float*)d_in[14];
    const float* Wf  = (const float*)d_in[15];
    const float* bf  = (const float*)d_in[16];
    const int* ei    = (const int*)d_in[17];
    const int* batch = (const int*)d_in[18];

    int N = in_sizes[0] / 16;
    int E = in_sizes[1] / 4;
    int nb = (N + 255) / 256;

    float* ws = (float*)d_ws;
    float* xn     = ws;                           // N*16
    float* h0     = xn + (size_t)N * 16;          // N*48
    float* h1     = h0 + (size_t)N * 48;          // N*48
    float* EA     = h1 + (size_t)N * 48;          // N*4
    float* estats = EA + (size_t)N * 4;           // 8
    float* xstats = estats + 8;                   // 32
    float* hcat   = xstats + 32;                  // 64*144
    int* deg        = (int*)(hcat + 64 * 144);    // N
    int* offsets    = deg + N;                    // N+1
    int* rank       = offsets + N + 1;            // E
    int* src_sorted = rank + E;                   // E
    int* eid_sorted = src_sorted + E;             // E
    int* bsum       = eid_sorted + E;             // 256
    int* boff       = bsum + 256;                 // 256

    // zero accumulators: estats(8)+xstats(32) contiguous; deg
    hipMemsetAsync(estats, 0, 40 * sizeof(float), stream);
    hipMemsetAsync(deg, 0, (size_t)N * sizeof(int), stream);

    int n4 = N * 4;  // float4 count of x
    xstats_kernel<<<256, 256, 0, stream>>>((const float4*)x, xstats, n4);
    xnorm_kernel<<<256, 256, 0, stream>>>((const float4*)x, (float4*)xn, xstats, n4, 1.f / N);
    edge_rank<<<2048, 256, 0, stream>>>((const float4*)eattr, ei, deg, rank, estats, E);
    scanA<<<nb, 256, 0, stream>>>(deg, offsets, bsum, N);
    scanB<<<1, 256, 0, stream>>>(bsum, boff, nb);
    scanC<<<nb, 256, 0, stream>>>(offsets, boff, N, E);
    edge_scatter<<<2048, 256, 0, stream>>>(ei, offsets, rank, src_sorted, eid_sorted, E);
    ea_sum<<<(N + 15) / 16, 256, 0, stream>>>((const float4*)eattr, offsets, eid_sorted, estats,
                                              (float4*)EA, N, 1.f / E);

    conv_kernel<16><<<(N + 3) / 4, 256, 0, stream>>>(xn, EA, offsets, src_sorted, Wr0, Wm0, b0, h0, N);
    readout_kernel<<<64, 256, 0, stream>>>(h0, batch, hcat, N, 0);
    conv_kernel<48><<<(N + 3) / 4, 256, 0, stream>>>(h0, EA, offsets, src_sorted, Wr1, Wm1, b1, h1, N);
    readout_kernel<<<64, 256, 0, stream>>>(h1, batch, hcat, N, 1);
    conv_kernel<48><<<(N + 3) / 4, 256, 0, stream>>>(h1, EA, offsets, src_sorted, Wr2, Wm2, b2, h0, N);
    readout_kernel<<<64, 256, 0, stream>>>(h0, batch, hcat, N, 2);

    mlp_kernel<<<64, 128, 0, stream>>>(hcat, Wl1, bl1, Wl2, bl2, Wf, bf, (float*)d_out);
}

// Round 4
// 624.333 us; speedup vs baseline: 1.7111x; 1.0891x over previous
//
#include <hip/hip_runtime.h>
#include <hip/hip_bf16.h>
#include <hip/hip_fp16.h>

#define LRELU(v) ((v) >= 0.f ? (v) : 0.2f * (v))

// ---------------- feature-norm stats for x ----------------
__global__ __launch_bounds__(256) void xstats_kernel(const float4* __restrict__ x4,
                                                     float* __restrict__ xstats, int n4) {
    __shared__ float ls[32];
    if (threadIdx.x < 32) ls[threadIdx.x] = 0.f;
    __syncthreads();
    float s1[4] = {0,0,0,0}, s2[4] = {0,0,0,0};
    int stride = gridDim.x * blockDim.x;
    int j4 = (threadIdx.x & 3) * 4;  // stride % 4 == 0 -> constant per thread
    for (int i = blockIdx.x * blockDim.x + threadIdx.x; i < n4; i += stride) {
        float4 v = x4[i];
        s1[0] += v.x; s2[0] += v.x * v.x;
        s1[1] += v.y; s2[1] += v.y * v.y;
        s1[2] += v.z; s2[2] += v.z * v.z;
        s1[3] += v.w; s2[3] += v.w * v.w;
    }
    #pragma unroll
    for (int k = 0; k < 4; ++k) {
        atomicAdd(&ls[j4 + k], s1[k]);
        atomicAdd(&ls[16 + j4 + k], s2[k]);
    }
    __syncthreads();
    if (threadIdx.x < 32) atomicAdd(&xstats[threadIdx.x], ls[threadIdx.x]);
}

// normalize x and store as fp16 (gather copy)
__global__ __launch_bounds__(256) void xnorm_kernel(const float4* __restrict__ x4,
                                                    __half2* __restrict__ xn2,
                                                    const float* __restrict__ xstats,
                                                    int n4, float invN) {
    int stride = gridDim.x * blockDim.x;
    for (int i = blockIdx.x * blockDim.x + threadIdx.x; i < n4; i += stride) {
        int j4 = (i & 3) * 4;
        float4 v = x4[i];
        float o[4], in[4] = {v.x, v.y, v.z, v.w};
        #pragma unroll
        for (int k = 0; k < 4; ++k) {
            float mu = xstats[j4 + k] * invN;
            float var = xstats[16 + j4 + k] * invN - mu * mu;
            o[k] = (in[k] - mu) * rsqrtf(var + 1e-5f);
        }
        xn2[2 * i]     = __floats2half2_rn(o[0], o[1]);
        xn2[2 * i + 1] = __floats2half2_rn(o[2], o[3]);
    }
}

// ---------------- edge pass 1: rank capture, 4-way unrolled for atomic ILP ----------------
// combo[e] = dst | (rank << 16)   (N < 65536, max in-degree << 65536)
__global__ __launch_bounds__(256) void edge_rank(const int* __restrict__ ei_dst,
                                                 int* __restrict__ deg,
                                                 unsigned* __restrict__ combo, int E) {
    int T = gridDim.x * blockDim.x;
    int tid = blockIdx.x * blockDim.x + threadIdx.x;
    for (int base = tid; base < E; base += 4 * T) {
        int e[4], d[4];
        bool ok[4];
        #pragma unroll
        for (int k = 0; k < 4; ++k) {
            e[k] = base + k * T;
            ok[k] = e[k] < E;
            d[k] = ok[k] ? ei_dst[e[k]] : 0;
        }
        unsigned r[4];
        #pragma unroll
        for (int k = 0; k < 4; ++k)
            if (ok[k]) r[k] = (unsigned)atomicAdd(&deg[d[k]], 1);
        #pragma unroll
        for (int k = 0; k < 4; ++k)
            if (ok[k]) combo[e[k]] = (unsigned)d[k] | (r[k] << 16);
    }
}

// ---------------- 3-phase exclusive scan of degrees ----------------
__global__ __launch_bounds__(256) void scanA(const int* __restrict__ deg,
                                             int* __restrict__ offs,
                                             int* __restrict__ bsum, int N) {
    int i = blockIdx.x * 256 + threadIdx.x;
    int v = (i < N) ? deg[i] : 0;
    int lane = threadIdx.x & 63, w = threadIdx.x >> 6;
    int inc = v;
    #pragma unroll
    for (int d = 1; d < 64; d <<= 1) {
        int u = __shfl_up(inc, d);
        if (lane >= d) inc += u;
    }
    __shared__ int wsum[4], woff[4];
    if (lane == 63) wsum[w] = inc;
    __syncthreads();
    if (threadIdx.x == 0) {
        int s = 0;
        #pragma unroll
        for (int k = 0; k < 4; ++k) { woff[k] = s; s += wsum[k]; }
        bsum[blockIdx.x] = s;
    }
    __syncthreads();
    if (i < N) offs[i] = woff[w] + inc - v;  // exclusive within block
}

__global__ __launch_bounds__(256) void scanB(const int* __restrict__ bsum,
                                             int* __restrict__ boff, int nb) {
    int t = threadIdx.x;
    int v = (t < nb) ? bsum[t] : 0;
    int lane = t & 63, w = t >> 6;
    int inc = v;
    #pragma unroll
    for (int d = 1; d < 64; d <<= 1) {
        int u = __shfl_up(inc, d);
        if (lane >= d) inc += u;
    }
    __shared__ int wsum[4], woff[4];
    if (lane == 63) wsum[w] = inc;
    __syncthreads();
    if (t == 0) {
        int s = 0;
        #pragma unroll
        for (int k = 0; k < 4; ++k) { woff[k] = s; s += wsum[k]; }
    }
    __syncthreads();
    if (t < nb) boff[t] = woff[w] + inc - v;
}

__global__ __launch_bounds__(256) void scanC(int* __restrict__ offs,
                                             const int* __restrict__ boff, int N, int E) {
    int i = blockIdx.x * 256 + threadIdx.x;
    if (i < N) offs[i] += boff[blockIdx.x];
    if (i == 0) offs[N] = E;
}

// ---------------- scatter src + eattr payload into dst-sorted CSR (atomic-free) + eattr stats ----------------
__global__ __launch_bounds__(256) void edge_scatter(const int* __restrict__ ei,
                                                    const unsigned* __restrict__ combo,
                                                    const float4* __restrict__ eattr,
                                                    const int* __restrict__ offsets,
                                                    int* __restrict__ src_sorted,
                                                    float4* __restrict__ ea_sorted,
                                                    float* __restrict__ estats, int E) {
    __shared__ float ls[8];
    if (threadIdx.x < 8) ls[threadIdx.x] = 0.f;
    __syncthreads();
    float s1[4] = {0,0,0,0}, s2[4] = {0,0,0,0};
    int stride = gridDim.x * blockDim.x;
    for (int e = blockIdx.x * blockDim.x + threadIdx.x; e < E; e += stride) {
        unsigned c = combo[e];
        int dst = (int)(c & 0xffffu);
        int r = (int)(c >> 16);
        int pos = offsets[dst] + r;
        float4 v = eattr[e];
        src_sorted[pos] = ei[e];
        ea_sorted[pos] = v;
        s1[0] += v.x; s2[0] += v.x * v.x;
        s1[1] += v.y; s2[1] += v.y * v.y;
        s1[2] += v.z; s2[2] += v.z * v.z;
        s1[3] += v.w; s2[3] += v.w * v.w;
    }
    #pragma unroll
    for (int k = 0; k < 4; ++k) {
        atomicAdd(&ls[k], s1[k]);
        atomicAdd(&ls[4 + k], s2[k]);
    }
    __syncthreads();
    if (threadIdx.x < 8) atomicAdd(&estats[threadIdx.x], ls[threadIdx.x]);
}

// ---------------- per-node edge-attr aggregation (coalesced) with analytic featnorm fold ----------------
__global__ __launch_bounds__(256) void ea_sum(const float4* __restrict__ ea_sorted,
                                              const int* __restrict__ offsets,
                                              const float* __restrict__ estats,
                                              float4* __restrict__ EA, int N, float invE) {
    int g = threadIdx.x >> 4, gl = threadIdx.x & 15;
    int node = blockIdx.x * 16 + g;
    if (node >= N) return;
    int s0 = offsets[node], s1 = offsets[node + 1];
    float4 acc = make_float4(0.f, 0.f, 0.f, 0.f);
    for (int e = s0 + gl; e < s1; e += 16) {
        float4 v = ea_sorted[e];
        acc.x += v.x; acc.y += v.y; acc.z += v.z; acc.w += v.w;
    }
    #pragma unroll
    for (int d = 1; d < 16; d <<= 1) {
        acc.x += __shfl_xor(acc.x, d);
        acc.y += __shfl_xor(acc.y, d);
        acc.z += __shfl_xor(acc.z, d);
        acc.w += __shfl_xor(acc.w, d);
    }
    if (gl == 0) {
        float degf = (float)(s1 - s0);
        float mu0 = estats[0] * invE, rs0 = rsqrtf(estats[4] * invE - mu0 * mu0 + 1e-5f);
        float mu1 = estats[1] * invE, rs1 = rsqrtf(estats[5] * invE - mu1 * mu1 + 1e-5f);
        float mu2 = estats[2] * invE, rs2 = rsqrtf(estats[6] * invE - mu2 * mu2 + 1e-5f);
        float mu3 = estats[3] * invE, rs3 = rsqrtf(estats[7] * invE - mu3 * mu3 + 1e-5f);
        float4 o;
        o.x = (acc.x - degf * mu0) * rs0;
        o.y = (acc.y - degf * mu1) * rs1;
        o.z = (acc.z - degf * mu2) * rs2;
        o.w = (acc.w - degf * mu3) * rs3;
        EA[node] = o;
    }
}

// ---------------- fused conv layer: fp16 CSR gather + node update ----------------
// one wave per node; 8 groups of 8 lanes; group = edge slot, lane%8 = half2 feature pair
template <int FIN>
__global__ __launch_bounds__(256) void conv_kernel(const __half* __restrict__ hin,
                                                   const float4* __restrict__ EA,
                                                   const int* __restrict__ offsets,
                                                   const int* __restrict__ src_sorted,
                                                   const float* __restrict__ Wr,
                                                   const float* __restrict__ Wm,
                                                   const float* __restrict__ b,
                                                   __half* __restrict__ hout, int N) {
    __shared__ float gbuf[4][48];
    __shared__ float hbuf[4][48];
    int w = threadIdx.x >> 6;
    int lane = threadIdx.x & 63;
    int node = blockIdx.x * 4 + w;
    if (node < N) {
        int s0 = offsets[node], s1 = offsets[node + 1];
        int g = lane >> 3, j = lane & 7;
        float2 a0 = {0.f, 0.f}, a1 = {0.f, 0.f}, a2 = {0.f, 0.f};
        for (int e = s0 + g; e < s1; e += 8) {
            int s = src_sorted[e];
            const __half2* hp = (const __half2*)(hin + (size_t)s * FIN);
            float2 v0 = __half22float2(hp[j]);
            a0.x += v0.x; a0.y += v0.y;
            if (FIN > 16) {
                float2 v1 = __half22float2(hp[8 + j]);
                float2 v2 = __half22float2(hp[16 + j]);
                a1.x += v1.x; a1.y += v1.y;
                a2.x += v2.x; a2.y += v2.y;
            }
        }
        #pragma unroll
        for (int m = 8; m < 64; m <<= 1) {
            a0.x += __shfl_xor(a0.x, m); a0.y += __shfl_xor(a0.y, m);
            if (FIN > 16) {
                a1.x += __shfl_xor(a1.x, m); a1.y += __shfl_xor(a1.y, m);
                a2.x += __shfl_xor(a2.x, m); a2.y += __shfl_xor(a2.y, m);
            }
        }
        if (g == 0) {
            gbuf[w][2 * j] = a0.x; gbuf[w][2 * j + 1] = a0.y;
            if (FIN > 16) {
                gbuf[w][16 + 2 * j] = a1.x; gbuf[w][17 + 2 * j] = a1.y;
                gbuf[w][32 + 2 * j] = a2.x; gbuf[w][33 + 2 * j] = a2.y;
            }
        }
        if (lane < FIN) hbuf[w][lane] = __half2float(hin[(size_t)node * FIN + lane]);
    }
    __syncthreads();
    if (node < N && lane < 48) {
        int f = lane;
        float acc = b[f];
        #pragma unroll
        for (int k = 0; k < FIN; ++k)
            acc += hbuf[w][k] * Wr[k * 48 + f] + gbuf[w][k] * Wm[k * 48 + f];
        float4 ea = EA[node];
        acc += ea.x * Wm[(FIN + 0) * 48 + f] + ea.y * Wm[(FIN + 1) * 48 + f]
             + ea.z * Wm[(FIN + 2) * 48 + f] + ea.w * Wm[(FIN + 3) * 48 + f];
        hout[(size_t)node * 48 + f] = __float2half(LRELU(acc));
    }
}

// ---------------- per-graph mean readout (batch is sorted, fp16 h) ----------------
__global__ __launch_bounds__(256) void readout_kernel(const __half* __restrict__ h,
                                                      const int* __restrict__ batch,
                                                      float* __restrict__ hcat, int N, int l) {
    int g = blockIdx.x;
    int lo = 0, hi = N;
    while (lo < hi) { int m = (lo + hi) >> 1; if (batch[m] < g) lo = m + 1; else hi = m; }
    int start = lo;
    hi = N;
    while (lo < hi) { int m = (lo + hi) >> 1; if (batch[m] < g + 1) lo = m + 1; else hi = m; }
    int end = lo;
    __shared__ float sred[4][48];
    int w = threadIdx.x >> 6, lane = threadIdx.x & 63;
    float acc = 0.f;
    if (lane < 48)
        for (int n = start + w; n < end; n += 4) acc += __half2float(h[(size_t)n * 48 + lane]);
    if (lane < 48) sred[w][lane] = acc;
    __syncthreads();
    int t = threadIdx.x;
    if (t < 48) {
        float s = sred[0][t] + sred[1][t] + sred[2][t] + sred[3][t];
        float cnt = (float)(end - start);
        hcat[g * 144 + l * 48 + t] = s / fmaxf(cnt, 1.f);
    }
}

// ---------------- final MLP: one block per graph ----------------
__global__ __launch_bounds__(128) void mlp_kernel(const float* __restrict__ hcat,
                                                  const float* __restrict__ Wl1, const float* __restrict__ bl1,
                                                  const float* __restrict__ Wl2, const float* __restrict__ bl2,
                                                  const float* __restrict__ Wf, const float* __restrict__ bf,
                                                  float* __restrict__ out) {
    int g = blockIdx.x, t = threadIdx.x;
    __shared__ float buf[144];
    __shared__ float l1[128];
    for (int i = t; i < 144; i += 128) buf[i] = hcat[g * 144 + i];
    __syncthreads();
    float acc = bl1[t];
    for (int k = 0; k < 144; ++k) acc += buf[k] * Wl1[k * 128 + t];
    acc = LRELU(acc);
    l1[t] = acc;
    __syncthreads();
    float acc2 = bl2[t];
    for (int k = 0; k < 128; ++k) acc2 += l1[k] * Wl2[k * 128 + t];
    acc2 = LRELU(acc2);
    __syncthreads();
    buf[t] = acc2;
    __syncthreads();
    if (t < 4) {
        float a = bf[t];
        for (int k = 0; k < 128; ++k) a += buf[k] * Wf[k * 4 + t];
        out[g * 4 + t] = a;
    }
}

extern "C" void kernel_launch(void* const* d_in, const int* in_sizes, int n_in,
                              void* d_out, int out_size, void* d_ws, size_t ws_size,
                              hipStream_t stream) {
    const float* x     = (const float*)d_in[0];
    const float* eattr = (const float*)d_in[1];
    const float* Wr0 = (const float*)d_in[2];
    const float* Wm0 = (const float*)d_in[3];
    const float* b0  = (const float*)d_in[4];
    const float* Wr1 = (const float*)d_in[5];
    const float* Wm1 = (const float*)d_in[6];
    const float* b1  = (const float*)d_in[7];
    const float* Wr2 = (const float*)d_in[8];
    const float* Wm2 = (const float*)d_in[9];
    const float* b2  = (const float*)d_in[10];
    const float* Wl1 = (const float*)d_in[11];
    const float* bl1 = (const float*)d_in[12];
    const float* Wl2 = (const float*)d_in[13];
    const float* bl2 = (const float*)d_in[14];
    const float* Wf  = (const float*)d_in[15];
    const float* bf  = (const float*)d_in[16];
    const int* ei    = (const int*)d_in[17];
    const int* batch = (const int*)d_in[18];

    int N = in_sizes[0] / 16;
    int E = in_sizes[1] / 4;
    int nb = (N + 255) / 256;

    // ---- workspace layout (float4 arrays first for 16B alignment) ----
    float4* ea_sorted = (float4*)d_ws;                        // E
    float4* EA        = ea_sorted + E;                        // N
    float*  hcat      = (float*)(EA + N);                     // 64*144
    float*  estats    = hcat + 64 * 144;                      // 8
    float*  xstats    = estats + 8;                           // 32
    __half* xn        = (__half*)(xstats + 32);               // N*16
    __half* h16a      = xn + (size_t)N * 16;                  // N*48
    __half* h16b      = h16a + (size_t)N * 48;                // N*48
    int* deg        = (int*)(h16b + (size_t)N * 48);          // N
    int* offsets    = deg + N;                                // N+1
    unsigned* combo = (unsigned*)(offsets + N + 1);           // E
    int* src_sorted = (int*)(combo + E);                      // E
    int* bsum       = src_sorted + E;                         // 256
    int* boff       = bsum + 256;                             // 256

    hipMemsetAsync(estats, 0, 40 * sizeof(float), stream);    // estats + xstats
    hipMemsetAsync(deg, 0, (size_t)N * sizeof(int), stream);

    int n4 = N * 4;  // float4 count of x
    xstats_kernel<<<256, 256, 0, stream>>>((const float4*)x, xstats, n4);
    xnorm_kernel<<<256, 256, 0, stream>>>((const float4*)x, (__half2*)xn, xstats, n4, 1.f / N);
    edge_rank<<<2048, 256, 0, stream>>>(ei + E, deg, combo, E);
    scanA<<<nb, 256, 0, stream>>>(deg, offsets, bsum, N);
    scanB<<<1, 256, 0, stream>>>(bsum, boff, nb);
    scanC<<<nb, 256, 0, stream>>>(offsets, boff, N, E);
    edge_scatter<<<2048, 256, 0, stream>>>(ei, combo, (const float4*)eattr, offsets,
                                           src_sorted, ea_sorted, estats, E);
    ea_sum<<<(N + 15) / 16, 256, 0, stream>>>(ea_sorted, offsets, estats, EA, N, 1.f / E);

    conv_kernel<16><<<(N + 3) / 4, 256, 0, stream>>>(xn, EA, offsets, src_sorted, Wr0, Wm0, b0, h16a, N);
    readout_kernel<<<64, 256, 0, stream>>>(h16a, batch, hcat, N, 0);
    conv_kernel<48><<<(N + 3) / 4, 256, 0, stream>>>(h16a, EA, offsets, src_sorted, Wr1, Wm1, b1, h16b, N);
    readout_kernel<<<64, 256, 0, stream>>>(h16b, batch, hcat, N, 1);
    conv_kernel<48><<<(N + 3) / 4, 256, 0, stream>>>(h16b, EA, offsets, src_sorted, Wr2, Wm2, b2, h16a, N);
    readout_kernel<<<64, 256, 0, stream>>>(h16a, batch, hcat, N, 2);

    mlp_kernel<<<64, 128, 0, stream>>>(hcat, Wl1, bl1, Wl2, bl2, Wf, bf, (float*)d_out);
}